// Round 19
// baseline (54.013 us; speedup 1.0000x reference)
//
#include <hip/hip_runtime.h>

#define HOG_PI  3.14159265358979323846f
#define HOG_PI2 1.57079632679489661923f

typedef float f2 __attribute__((ext_vector_type(2)));

__device__ __forceinline__ float dpp_from_left(float x) {  // lane i <- lane i-1
  return __int_as_float(__builtin_amdgcn_mov_dpp(__float_as_int(x), 0x130, 0xF, 0xF, true));
}
__device__ __forceinline__ float dpp_from_right(float x) {  // lane i <- lane i+1
  return __int_as_float(__builtin_amdgcn_mov_dpp(__float_as_int(x), 0x138, 0xF, 0xF, true));
}

// One scalar pixel tail: angle reconstruction -> bin scatter to LDS row.
__device__ __forceinline__ void px_tail(
    float dxs, float dys, float g, float base, float* __restrict__ row) {
  const float mag = __builtin_amdgcn_sqrtf(g);
  const bool oct = fabsf(dys) > fabsf(dxs);
  float th = oct ? (HOG_PI2 - base) : base;
  if (dxs * dys < 0.0f) th = HOG_PI - th;
  const float pos = th * (9.0f / HOG_PI) - 0.5f;  // [-0.5, 8.5]
  const float bf = floorf(pos);
  const float frac = pos - bf;
  const int b0 = (int)bf;             // [-1, 8]
  const int b0i = (b0 < 0) ? 8 : b0;  // partner always b0i+1 (bin9 = alias 0)
  const float w0 = mag * (1.0f - frac);
  const float w1 = mag * frac;
  float* p = row + b0i;
  const float a0 = p[0];  // ds_read2_b32
  const float a1 = p[1];
  p[0] = a0 + w0;         // ds_write2_b32
  p[1] = a1 + w1;
}

// Accumulate 4 pixels (one float4 column), PAIR-MAJOR (peak live regs ~58:
// only one pair's dx/dy/g [9 f2] alive at a time -> fits the 64-VGPR cap
// that 8 waves/SIMD requires). Packed math for gradients + atan poly.
__device__ __forceinline__ void accum_quad(
    const float4 c0, const float4 c1, const float4 c2,
    const float4 p0, const float4 p1, const float4 p2,
    const float4 n0, const float4 n1, const float4 n2,
    int xq, float* __restrict__ partT) {
#pragma unroll
  for (int p = 0; p < 2; ++p) {  // pixel pairs (2p, 2p+1)
    f2 dx[3], dy[3], g[3];
#pragma unroll
    for (int c = 0; c < 3; ++c) {
      const float4 cc = (c == 0) ? c0 : (c == 1) ? c1 : c2;
      const float4 pp = (c == 0) ? p0 : (c == 1) ? p1 : p2;
      const float4 nn = (c == 0) ? n0 : (c == 1) ? n1 : n2;
      if (p == 0) {
        float lf = dpp_from_left(cc.w);
        if (xq == 0) lf = cc.x;
        dx[c] = (f2){cc.y, cc.z} - (f2){lf, cc.x};
        dy[c] = (f2){nn.x, nn.y} - (f2){pp.x, pp.y};
      } else {
        float rf = dpp_from_right(cc.x);
        if (xq == 31) rf = cc.w;
        dx[c] = (f2){cc.w, rf} - (f2){cc.y, cc.z};
        dy[c] = (f2){nn.z, nn.w} - (f2){pp.z, pp.w};
      }
      g[c] = dx[c] * dx[c] + dy[c] * dy[c];  // pk_mul + pk_fma
    }
    // scalar argmax per half, first-max wins on ties (strict >)
    float dxsA = dx[0].x, dysA = dy[0].x, gA = g[0].x;
    if (g[1].x > gA) { dxsA = dx[1].x; dysA = dy[1].x; gA = g[1].x; }
    if (g[2].x > gA) { dxsA = dx[2].x; dysA = dy[2].x; gA = g[2].x; }
    float dxsB = dx[0].y, dysB = dy[0].y, gB = g[0].y;
    if (g[1].y > gB) { dxsB = dx[1].y; dysB = dy[1].y; gB = g[1].y; }
    if (g[2].y > gB) { dxsB = dx[2].y; dysB = dy[2].y; gB = g[2].y; }
    const float mnA = fminf(fabsf(dxsA), fabsf(dysA));
    const float mxA = fmaxf(fmaxf(fabsf(dxsA), fabsf(dysA)), 1e-30f);
    const float aA = mnA * __builtin_amdgcn_rcpf(mxA);
    const float mnB = fminf(fabsf(dxsB), fabsf(dysB));
    const float mxB = fmaxf(fmaxf(fabsf(dxsB), fabsf(dysB)), 1e-30f);
    const float aB = mnB * __builtin_amdgcn_rcpf(mxB);
    const f2 av = {aA, aB};
    const f2 sq = av * av;
    const f2 base =
        ((((f2)(0.0208351f) * sq - (f2)(0.0851330f)) * sq + (f2)(0.1801410f)) *
             sq - (f2)(0.3302995f)) * sq * av + (f2)(0.9998660f) * av;
    px_tail(dxsA, dysA, gA, base.x, partT);       // even px -> row 0
    px_tail(dxsB, dysB, gB, base.y, partT + 10);  // odd px -> row 1
  }
}

// One block per image, 1024 threads = 32 half-band slots (s=t>>5, 8 rows
// each) x 32 float4-cols (xq). Wave w: lanes 0-31 = upper half of band w,
// lanes 32-63 = lower half -> shfl_xor(32) merges halves for free.
// launch_bounds(1024,8): VGPR cap 64 -> 2 blocks/CU = 32 waves/CU (2x R16's
// TLP, the one untested axis). LDS 80 KB, cellh overlaid.
__global__ __launch_bounds__(1024, 8) void hog_kernel(
    const float* __restrict__ img, const int* __restrict__ targets,
    const int* __restrict__ camid, float* __restrict__ out, int B) {
  const int b = blockIdx.x;
  const int t = threadIdx.x;
  const float* im = img + (size_t)b * (3 * 256 * 128);

  __shared__ float lds[1024 * 20];  // 80 KB; scatter rows, later cellh overlay
  float* const partT = lds + t * 20;

  const int xq = t & 31;   // float4 column 0..31
  const int s = t >> 5;    // half-band slot 0..31; band = s>>1 = t>>6
  const int x0 = xq * 4;
  const int cx = xq >> 2;  // cell column 0..7
  const int r0 = s * 8;

#pragma unroll
  for (int j = 0; j < 20; ++j) partT[j] = 0.0f;

  const float* ch0 = im;
  const float* ch1 = im + 32768;
  const float* ch2 = im + 65536;

  const int rp = (r0 == 0) ? 0 : r0 - 1;
  float4 p0 = *(const float4*)(ch0 + rp * 128 + x0);
  float4 p1 = *(const float4*)(ch1 + rp * 128 + x0);
  float4 p2 = *(const float4*)(ch2 + rp * 128 + x0);
  float4 c0 = *(const float4*)(ch0 + r0 * 128 + x0);
  float4 c1 = *(const float4*)(ch1 + r0 * 128 + x0);
  float4 c2 = *(const float4*)(ch2 + r0 * 128 + x0);

#pragma unroll 1
  for (int r = 0; r < 8; ++r) {
    const int y = r0 + r;
    const int yn = (y == 255) ? 255 : y + 1;
    const float4 n0 = *(const float4*)(ch0 + yn * 128 + x0);
    const float4 n1 = *(const float4*)(ch1 + yn * 128 + x0);
    const float4 n2 = *(const float4*)(ch2 + yn * 128 + x0);

    accum_quad(c0, c1, c2, p0, p1, p2, n0, n1, n2, xq, partT);

    p0 = c0; p1 = c1; p2 = c2;
    c0 = n0; c1 = n1; c2 = n2;
  }

  // flush: merge 2 rows + fold bin9 into bin0 (reads BEFORE the barrier so
  // the cellh overlay can't clobber unread data), reduce 4 xq-lanes, then
  // shfl_xor(32) merges the two half-bands of this wave's band.
  float hv[9];
#pragma unroll
  for (int k = 0; k < 9; ++k) hv[k] = partT[k] + partT[10 + k];
  hv[0] += partT[9] + partT[19];
  __syncthreads();

  float (*cellh)[8][9] = (float (*)[8][9])lds;  // overlay
  const int lane = t & 63;
#pragma unroll
  for (int k = 0; k < 9; ++k) {
    float v = hv[k];
    v += __shfl_xor(v, 1, 64);
    v += __shfl_xor(v, 2, 64);
    v += __shfl_xor(v, 32, 64);  // upper half-band + lower half-band
    if ((xq & 3) == 0 && lane < 32) cellh[t >> 6][cx][k] = v;
  }
  __syncthreads();

  float* outF = out + (size_t)b * 4096;
  if (t < 105) {
    const int by = t / 7;
    const int bx = t - by * 7;
    float v[36];
#pragma unroll
    for (int q = 0; q < 4; ++q) {
      const int cy = by + (q >> 1);
      const int ccx = bx + (q & 1);
#pragma unroll
      for (int k = 0; k < 9; ++k) v[q * 9 + k] = cellh[cy][ccx][k];
    }
    float ss = 0.0f;
#pragma unroll
    for (int jj = 0; jj < 36; ++jj) ss += v[jj] * v[jj];
    const float s1 = 1.0f / (sqrtf(ss) + 3.6f);  // sz*0.1 = 36*0.1
    float ss2 = 0.0f;
#pragma unroll
    for (int jj = 0; jj < 36; ++jj) {
      v[jj] = fminf(v[jj] * s1, 0.2f);
      ss2 += v[jj] * v[jj];
    }
    const float s2 = 1.0f / (sqrtf(ss2) + 1e-3f);
    float4* dst = (float4*)(outF + (by * 7 + bx) * 36);
#pragma unroll
    for (int q = 0; q < 9; ++q)
      dst[q] = make_float4(v[4 * q] * s2, v[4 * q + 1] * s2,
                           v[4 * q + 2] * s2, v[4 * q + 3] * s2);
  }
  // zero the pad region [3780, 4096)
  for (int i = 3780 + t; i < 4096; i += 1024) outF[i] = 0.0f;
  // passthrough outputs
  if (t == 400) out[(size_t)B * 4096 + b] = (float)targets[b];
  if (t == 401) out[(size_t)B * 4096 + B + b] = (float)camid[b];
}

extern "C" void kernel_launch(void* const* d_in, const int* in_sizes, int n_in,
                              void* d_out, int out_size, void* d_ws, size_t ws_size,
                              hipStream_t stream) {
  const float* images = (const float*)d_in[0];
  const int* targets = (const int*)d_in[1];
  const int* camid = (const int*)d_in[2];
  float* out = (float*)d_out;
  const int B = in_sizes[1];  // 512
  hipLaunchKernelGGL(hog_kernel, dim3(B), dim3(1024), 0, stream,
                     images, targets, camid, out, B);
}

// Round 20
// 43.677 us; speedup vs baseline: 1.2367x; 1.2367x over previous
//
#include <hip/hip_runtime.h>

#define HOG_PI  3.14159265358979323846f
#define HOG_PI2 1.57079632679489661923f

typedef float f2 __attribute__((ext_vector_type(2)));

__device__ __forceinline__ float dpp_from_left(float x) {  // lane i <- lane i-1
  return __int_as_float(__builtin_amdgcn_mov_dpp(__float_as_int(x), 0x130, 0xF, 0xF, true));
}
__device__ __forceinline__ float dpp_from_right(float x) {  // lane i <- lane i+1
  return __int_as_float(__builtin_amdgcn_mov_dpp(__float_as_int(x), 0x138, 0xF, 0xF, true));
}

// One scalar pixel tail: angle reconstruction -> bin scatter to LDS row.
__device__ __forceinline__ void px_tail(
    float dxs, float dys, float g, float base, float* __restrict__ row) {
  const float mag = __builtin_amdgcn_sqrtf(g);
  const bool oct = fabsf(dys) > fabsf(dxs);
  float th = oct ? (HOG_PI2 - base) : base;
  if (dxs * dys < 0.0f) th = HOG_PI - th;
  const float pos = th * (9.0f / HOG_PI) - 0.5f;  // [-0.5, 8.5]
  const float bf = floorf(pos);
  const float frac = pos - bf;
  const int b0 = (int)bf;             // [-1, 8]
  const int b0i = (b0 < 0) ? 8 : b0;  // partner always b0i+1 (bin9 = alias 0)
  const float w0 = mag * (1.0f - frac);
  const float w1 = mag * frac;
  float* p = row + b0i;
  const float a0 = p[0];  // ds_read2_b32
  const float a1 = p[1];
  p[0] = a0 + w0;         // ds_write2_b32
  p[1] = a1 + w1;
}

// Accumulate 2 pixels (one float2 column) into thread-private LDS rows.
// Window is float2 per channel -> register backbone 18 VGPR (vs 36 float4),
// the key to fitting the 64-VGPR cap WITHOUT spills (R19's failure).
__device__ __forceinline__ void accum_pair(
    const f2 c0, const f2 c1, const f2 c2,
    const f2 p0, const f2 p1, const f2 p2,
    const f2 n0, const f2 n1, const f2 n2,
    int xq, float* __restrict__ partT) {
  f2 dx[3], dy[3], g[3];
#pragma unroll
  for (int c = 0; c < 3; ++c) {
    const f2 cc = (c == 0) ? c0 : (c == 1) ? c1 : c2;
    const f2 pp = (c == 0) ? p0 : (c == 1) ? p1 : p2;
    const f2 nn = (c == 0) ? n0 : (c == 1) ? n1 : n2;
    float lf = dpp_from_left(cc.y);   // prev lane's right pixel
    float rf = dpp_from_right(cc.x);  // next lane's left pixel
    if (xq == 0) lf = cc.x;           // edge clamp overrides boundary lanes
    if (xq == 63) rf = cc.y;
    dx[c] = (f2){cc.y, rf} - (f2){lf, cc.x};  // v_pk_add (neg)
    dy[c] = nn - pp;                          // v_pk_add
    g[c] = dx[c] * dx[c] + dy[c] * dy[c];     // pk_mul + pk_fma
  }
  // scalar argmax per pixel, first-max wins on ties (strict >)
  float dxsA = dx[0].x, dysA = dy[0].x, gA = g[0].x;
  if (g[1].x > gA) { dxsA = dx[1].x; dysA = dy[1].x; gA = g[1].x; }
  if (g[2].x > gA) { dxsA = dx[2].x; dysA = dy[2].x; gA = g[2].x; }
  float dxsB = dx[0].y, dysB = dy[0].y, gB = g[0].y;
  if (g[1].y > gB) { dxsB = dx[1].y; dysB = dy[1].y; gB = g[1].y; }
  if (g[2].y > gB) { dxsB = dx[2].y; dysB = dy[2].y; gB = g[2].y; }
  const float mnA = fminf(fabsf(dxsA), fabsf(dysA));
  const float mxA = fmaxf(fmaxf(fabsf(dxsA), fabsf(dysA)), 1e-30f);
  const float aA = mnA * __builtin_amdgcn_rcpf(mxA);
  const float mnB = fminf(fabsf(dxsB), fabsf(dysB));
  const float mxB = fmaxf(fmaxf(fabsf(dxsB), fabsf(dysB)), 1e-30f);
  const float aB = mnB * __builtin_amdgcn_rcpf(mxB);
  const f2 av = {aA, aB};
  const f2 sq = av * av;
  const f2 base =
      ((((f2)(0.0208351f) * sq - (f2)(0.0851330f)) * sq + (f2)(0.1801410f)) *
           sq - (f2)(0.3302995f)) * sq * av + (f2)(0.9998660f) * av;
  px_tail(dxsA, dysA, gA, base.x, partT);       // even px -> row 0
  px_tail(dxsB, dysB, gB, base.y, partT + 10);  // odd px -> row 1
}

// One block per image, 1024 threads = 16 bands (m=t>>6) x 64 float2-cols
// (xq=t&63). Wave = one full band (clean dpp halo across all 64 lanes).
// launch_bounds(1024,8): VGPR cap 64; float2 window makes it FIT (no spill)
// -> LDS 80KB x 2 = 160KB -> 2 blocks/CU = 32 waves/CU (2x R16's TLP).
__global__ __launch_bounds__(1024, 8) void hog_kernel(
    const float* __restrict__ img, const int* __restrict__ targets,
    const int* __restrict__ camid, float* __restrict__ out, int B) {
  const int b = blockIdx.x;
  const int t = threadIdx.x;
  const float* im = img + (size_t)b * (3 * 256 * 128);

  __shared__ float lds[1024 * 20];  // 80 KB; scatter rows, later cellh overlay
  float* const partT = lds + t * 20;

  const int xq = t & 63;   // float2 column 0..63
  const int m = t >> 6;    // cell band 0..15 (= wave id)
  const int x0 = xq * 2;
  const int cx = xq >> 3;  // cell column 0..7
  const int r0 = m * 16;

#pragma unroll
  for (int j = 0; j < 20; ++j) partT[j] = 0.0f;

  const float* ch0 = im;
  const float* ch1 = im + 32768;
  const float* ch2 = im + 65536;

  const int rp = (r0 == 0) ? 0 : r0 - 1;
  f2 p0 = *(const f2*)(ch0 + rp * 128 + x0);
  f2 p1 = *(const f2*)(ch1 + rp * 128 + x0);
  f2 p2 = *(const f2*)(ch2 + rp * 128 + x0);
  f2 c0 = *(const f2*)(ch0 + r0 * 128 + x0);
  f2 c1 = *(const f2*)(ch1 + r0 * 128 + x0);
  f2 c2 = *(const f2*)(ch2 + r0 * 128 + x0);
  f2 n0 = *(const f2*)(ch0 + (r0 + 1) * 128 + x0);
  f2 n1 = *(const f2*)(ch1 + (r0 + 1) * 128 + x0);
  f2 n2 = *(const f2*)(ch2 + (r0 + 1) * 128 + x0);

#pragma unroll 1
  for (int r = 0; r < 16; ++r) {
    // prefetch row r+1's 'n' (row y+2, clamped); issued before any use of n*
    const int y2 = r0 + r + 2;
    const int yc = (y2 > 255) ? 255 : y2;
    const f2 f0 = *(const f2*)(ch0 + yc * 128 + x0);
    const f2 f1 = *(const f2*)(ch1 + yc * 128 + x0);
    const f2 f2v = *(const f2*)(ch2 + yc * 128 + x0);

    accum_pair(c0, c1, c2, p0, p1, p2, n0, n1, n2, xq, partT);

    p0 = c0; p1 = c1; p2 = c2;
    c0 = n0; c1 = n1; c2 = n2;
    n0 = f0; n1 = f1; n2 = f2v;
  }

  // flush: merge 2 rows + fold bin9 (unwrapped) into bin0; reads into regs
  // BEFORE the barrier so the cellh overlay can't clobber unread data
  float hv[9];
#pragma unroll
  for (int k = 0; k < 9; ++k) hv[k] = partT[k] + partT[10 + k];
  hv[0] += partT[9] + partT[19];
  __syncthreads();

  float (*cellh)[8][9] = (float (*)[8][9])lds;  // overlay
#pragma unroll
  for (int k = 0; k < 9; ++k) {
    float v = hv[k];
    v += __shfl_xor(v, 1, 64);  // reduce the 8 lanes of this cell column
    v += __shfl_xor(v, 2, 64);
    v += __shfl_xor(v, 4, 64);
    if ((xq & 7) == 0) cellh[m][cx][k] = v;
  }
  __syncthreads();

  float* outF = out + (size_t)b * 4096;
  if (t < 105) {
    const int by = t / 7;
    const int bx = t - by * 7;
    float v[36];
#pragma unroll
    for (int q = 0; q < 4; ++q) {
      const int cy = by + (q >> 1);
      const int ccx = bx + (q & 1);
#pragma unroll
      for (int k = 0; k < 9; ++k) v[q * 9 + k] = cellh[cy][ccx][k];
    }
    float ss = 0.0f;
#pragma unroll
    for (int jj = 0; jj < 36; ++jj) ss += v[jj] * v[jj];
    const float s1 = 1.0f / (sqrtf(ss) + 3.6f);  // sz*0.1 = 36*0.1
    float ss2 = 0.0f;
#pragma unroll
    for (int jj = 0; jj < 36; ++jj) {
      v[jj] = fminf(v[jj] * s1, 0.2f);
      ss2 += v[jj] * v[jj];
    }
    const float s2 = 1.0f / (sqrtf(ss2) + 1e-3f);
    float4* dst = (float4*)(outF + (by * 7 + bx) * 36);
#pragma unroll
    for (int q = 0; q < 9; ++q)
      dst[q] = make_float4(v[4 * q] * s2, v[4 * q + 1] * s2,
                           v[4 * q + 2] * s2, v[4 * q + 3] * s2);
  }
  // zero the pad region [3780, 4096)
  for (int i = 3780 + t; i < 4096; i += 1024) outF[i] = 0.0f;
  // passthrough outputs
  if (t == 400) out[(size_t)B * 4096 + b] = (float)targets[b];
  if (t == 401) out[(size_t)B * 4096 + B + b] = (float)camid[b];
}

extern "C" void kernel_launch(void* const* d_in, const int* in_sizes, int n_in,
                              void* d_out, int out_size, void* d_ws, size_t ws_size,
                              hipStream_t stream) {
  const float* images = (const float*)d_in[0];
  const int* targets = (const int*)d_in[1];
  const int* camid = (const int*)d_in[2];
  float* out = (float*)d_out;
  const int B = in_sizes[1];  // 512
  hipLaunchKernelGGL(hog_kernel, dim3(B), dim3(1024), 0, stream,
                     images, targets, camid, out, B);
}